// Round 1
// baseline (39.140 us; speedup 1.0000x reference)
//
#include <hip/hip_runtime.h>
#include <math.h>

#define KK 5
#define WPOUT 28
#define PPI 784          // patches per image (28*28)
#define NCH 64
#define NPATCH 25088     // 32*784
#define THREADS 256

// Evaluate one 4-input LUT node.
// lutrow (LDS, 16 floats): [0..7] = sigmoid(lut[2k]) ("even"), [8..15] = sigmoid(lut[2k+1]) - sigmoid(lut[2k]) ("diff")
// Bit order: s0 is the most significant address bit (contracted last), s3 least significant (contracted first).
__device__ __forceinline__ float node_eval(const float* lutrow,
                                            float s0, float s1, float s2, float s3) {
    float v[8];
#pragma unroll
    for (int k = 0; k < 8; ++k) v[k] = fmaf(s3, lutrow[k + 8], lutrow[k]);
    float w[4];
#pragma unroll
    for (int k = 0; k < 4; ++k) w[k] = fmaf(s2, v[2 * k + 1] - v[2 * k], v[2 * k]);
    float u0 = fmaf(s1, w[1] - w[0], w[0]);
    float u1 = fmaf(s1, w[3] - w[2], w[2]);
    return fmaf(s0, u1 - u0, u0);
}

__global__ __launch_bounds__(THREADS, 4)
void dwn_conv_lut_kernel(const float* __restrict__ x,     // [32,1,32,32]
                         const float* __restrict__ lut0,  // [64,16,16]
                         const float* __restrict__ lut1,  // [64,4,16]
                         const float* __restrict__ lut2,  // [64,1,16]
                         const int*   __restrict__ idx0,  // [64,16,4]
                         const int*   __restrict__ idx1,  // [64,4,4]
                         const int*   __restrict__ idx2,  // [64,1,4]
                         float*       __restrict__ out)   // [32,64,28,28]
{
    __shared__ float l0[16][16];           // per node: e[8], d[8]
    __shared__ float l1[4][16];
    __shared__ float l2[16];
    __shared__ float scratch[THREADS * 25];  // per-thread private slice, stride 25 (coprime w/ 32 banks)

    const int tid = threadIdx.x;
    const int c   = blockIdx.y;

    // ---- stage sigmoided LUTs in (even, diff) layout: 168 pairs, one per thread ----
    if (tid < 168) {
        const float* src;
        float* dst;
        int k;
        if (tid < 128) {                     // lut0: 16 nodes * 8 pairs
            int node = tid >> 3; k = tid & 7;
            src = lut0 + (c * 16 + node) * 16;
            dst = &l0[node][0];
        } else if (tid < 160) {              // lut1: 4 nodes * 8 pairs
            int t = tid - 128;
            int node = t >> 3; k = t & 7;
            src = lut1 + (c * 4 + node) * 16;
            dst = &l1[node][0];
        } else {                             // lut2: 1 node * 8 pairs
            int t = tid - 160; k = t & 7;
            src = lut2 + c * 16;
            dst = l2;
        }
        float a = src[2 * k], b = src[2 * k + 1];
        float ea = 1.0f / (1.0f + __expf(-a));
        float eb = 1.0f / (1.0f + __expf(-b));
        dst[k]     = ea;
        dst[k + 8] = eb - ea;
    }

    // ---- load my 5x5 patch into my private LDS slice ----
    const int p = blockIdx.x * THREADS + tid;      // patch id, grid sized exactly: 98*256 == 25088
    const int b = p / PPI;
    const int q = p - b * PPI;
    const int i = q / WPOUT;
    const int j = q - i * WPOUT;
    const float* xb = x + b * 1024 + i * 32 + j;
    float* my = &scratch[tid * 25];
#pragma unroll
    for (int di = 0; di < KK; ++di) {
#pragma unroll
        for (int dj = 0; dj < KK; ++dj) {
            my[di * 5 + dj] = xb[di * 32 + dj];
        }
    }

    __syncthreads();   // l0/l1/l2 written by a subset, read by all

    // ---- layer 0: 16 nodes, inputs gathered from the 25 patch values ----
    const int* id0 = idx0 + c * 64;   // block-uniform addresses -> scalar loads
    float h0[16];
#pragma unroll
    for (int m = 0; m < 16; ++m) {
        const int i0 = id0[m * 4 + 0];
        const int i1 = id0[m * 4 + 1];
        const int i2 = id0[m * 4 + 2];
        const int i3 = id0[m * 4 + 3];
        h0[m] = node_eval(&l0[m][0], my[i0], my[i1], my[i2], my[i3]);
    }
    // overwrite my private slice with h0 (program order within a thread; no barrier needed)
#pragma unroll
    for (int m = 0; m < 16; ++m) my[m] = h0[m];

    // ---- layer 1: 4 nodes, inputs gathered from h0 (in my slice) ----
    const int* id1 = idx1 + c * 16;
    float h1[4];
#pragma unroll
    for (int m = 0; m < 4; ++m) {
        const int i0 = id1[m * 4 + 0];
        const int i1 = id1[m * 4 + 1];
        const int i2 = id1[m * 4 + 2];
        const int i3 = id1[m * 4 + 3];
        h1[m] = node_eval(&l1[m][0], my[i0], my[i1], my[i2], my[i3]);
    }

    // ---- layer 2: 1 node, inputs selected from h1 (registers, 4-way select) ----
    const int* id2 = idx2 + c * 4;
    float s[4];
#pragma unroll
    for (int jj = 0; jj < 4; ++jj) {
        const int ii = id2[jj];
        s[jj] = (ii == 0) ? h1[0] : (ii == 1) ? h1[1] : (ii == 2) ? h1[2] : h1[3];
    }
    const float res = node_eval(l2, s[0], s[1], s[2], s[3]);

    // out[b, c, q]
    out[(b * NCH + c) * PPI + q] = res;
}

extern "C" void kernel_launch(void* const* d_in, const int* in_sizes, int n_in,
                              void* d_out, int out_size, void* d_ws, size_t ws_size,
                              hipStream_t stream) {
    const float* x    = (const float*)d_in[0];
    const float* lut0 = (const float*)d_in[1];
    const float* lut1 = (const float*)d_in[2];
    const float* lut2 = (const float*)d_in[3];
    const int*   idx0 = (const int*)d_in[4];
    const int*   idx1 = (const int*)d_in[5];
    const int*   idx2 = (const int*)d_in[6];
    float* out = (float*)d_out;

    dim3 grid(NPATCH / THREADS, NCH);   // 98 x 64
    dim3 block(THREADS);
    dwn_conv_lut_kernel<<<grid, block, 0, stream>>>(x, lut0, lut1, lut2,
                                                    idx0, idx1, idx2, out);
}

// Round 2
// 34.095 us; speedup vs baseline: 1.1480x; 1.1480x over previous
//
#include <hip/hip_runtime.h>
#include <math.h>

#define KK 5
#define WPOUT 28
#define PPI 784          // patches per image (28*28)
#define NCH 64
#define NPATCH 25088     // 32*784
#define THREADS 256

typedef float f32x32 __attribute__((ext_vector_type(32)));
typedef float f32x16 __attribute__((ext_vector_type(16)));

// Evaluate one 4-input LUT node.
// lutrow (LDS, 16 floats, block-uniform address): [0..7] = sigmoid(lut[2k]),
// [8..15] = sigmoid(lut[2k+1]) - sigmoid(lut[2k]).
// s0 = most significant address bit (contracted last), s3 least significant.
__device__ __forceinline__ float node_eval(const float* lutrow,
                                            float s0, float s1, float s2, float s3) {
    float v[8];
#pragma unroll
    for (int k = 0; k < 8; ++k) v[k] = fmaf(s3, lutrow[k + 8], lutrow[k]);
    float w[4];
#pragma unroll
    for (int k = 0; k < 4; ++k) w[k] = fmaf(s2, v[2 * k + 1] - v[2 * k], v[2 * k]);
    float u0 = fmaf(s1, w[1] - w[0], w[0]);
    float u1 = fmaf(s1, w[3] - w[2], w[2]);
    return fmaf(s0, u1 - u0, u0);
}

__global__ __launch_bounds__(THREADS, 4)
void dwn_conv_lut_kernel(const float* __restrict__ x,     // [32,1,32,32]
                         const float* __restrict__ lut0,  // [64,16,16]
                         const float* __restrict__ lut1,  // [64,4,16]
                         const float* __restrict__ lut2,  // [64,1,16]
                         const int*   __restrict__ idx0,  // [64,16,4]
                         const int*   __restrict__ idx1,  // [64,4,4]
                         const int*   __restrict__ idx2,  // [64,1,4]
                         float*       __restrict__ out)   // [32,64,28,28]
{
    __shared__ float l0[16][16];           // per node: e[8], d[8]
    __shared__ float l1[4][16];
    __shared__ float l2[16];

    const int tid = threadIdx.x;
    const int c   = blockIdx.y;

    // ---- stage sigmoided LUTs in (even, diff) layout: 168 pairs, one per thread ----
    if (tid < 168) {
        const float* src;
        float* dst;
        int k;
        if (tid < 128) {                     // lut0: 16 nodes * 8 pairs
            int node = tid >> 3; k = tid & 7;
            src = lut0 + (c * 16 + node) * 16;
            dst = &l0[node][0];
        } else if (tid < 160) {              // lut1: 4 nodes * 8 pairs
            int t = tid - 128;
            int node = t >> 3; k = t & 7;
            src = lut1 + (c * 4 + node) * 16;
            dst = &l1[node][0];
        } else {                             // lut2: 1 node * 8 pairs
            int t = tid - 160; k = t & 7;
            src = lut2 + c * 16;
            dst = l2;
        }
        float a = src[2 * k], b = src[2 * k + 1];
        float ea = 1.0f / (1.0f + __expf(-a));
        float eb = 1.0f / (1.0f + __expf(-b));
        dst[k]     = ea;
        dst[k + 8] = eb - ea;
    }

    // ---- load my 5x5 patch into a register-resident vector (movrel-gatherable) ----
    const int p = blockIdx.x * THREADS + tid;      // 98*256 == 25088, no tail
    const int b = p / PPI;
    const int q = p - b * PPI;
    const int i = q / WPOUT;
    const int j = q - i * WPOUT;
    const float* xb = x + b * 1024 + i * 32 + j;

    f32x32 pv;
#pragma unroll
    for (int di = 0; di < KK; ++di) {
#pragma unroll
        for (int dj = 0; dj < KK; ++dj) {
            pv[di * 5 + dj] = xb[di * 32 + dj];   // constant insert index
        }
    }

    __syncthreads();   // l0/l1/l2 ready

    // ---- layer 0: 16 nodes; gathers are uniform-index movrel reads from pv ----
    const int* id0 = idx0 + c * 64;   // block-uniform -> scalar loads
    f32x16 h0;
#pragma unroll
    for (int m = 0; m < 16; ++m) {
        const int i0 = __builtin_amdgcn_readfirstlane(id0[m * 4 + 0]);
        const int i1 = __builtin_amdgcn_readfirstlane(id0[m * 4 + 1]);
        const int i2 = __builtin_amdgcn_readfirstlane(id0[m * 4 + 2]);
        const int i3 = __builtin_amdgcn_readfirstlane(id0[m * 4 + 3]);
        h0[m] = node_eval(&l0[m][0], pv[i0], pv[i1], pv[i2], pv[i3]);
    }

    // ---- layer 1: 4 nodes; uniform-index movrel reads from h0 ----
    const int* id1 = idx1 + c * 16;
    float h1[4];
#pragma unroll
    for (int m = 0; m < 4; ++m) {
        const int i0 = __builtin_amdgcn_readfirstlane(id1[m * 4 + 0]);
        const int i1 = __builtin_amdgcn_readfirstlane(id1[m * 4 + 1]);
        const int i2 = __builtin_amdgcn_readfirstlane(id1[m * 4 + 2]);
        const int i3 = __builtin_amdgcn_readfirstlane(id1[m * 4 + 3]);
        h0[m] = h0[m]; // no-op to keep unroll clean
        h1[m] = node_eval(&l1[m][0], h0[i0], h0[i1], h0[i2], h0[i3]);
    }

    // ---- layer 2: 1 node; 4-way uniform select from h1 ----
    const int* id2 = idx2 + c * 4;
    float s[4];
#pragma unroll
    for (int jj = 0; jj < 4; ++jj) {
        const int ii = __builtin_amdgcn_readfirstlane(id2[jj]);
        s[jj] = (ii == 0) ? h1[0] : (ii == 1) ? h1[1] : (ii == 2) ? h1[2] : h1[3];
    }
    const float res = node_eval(l2, s[0], s[1], s[2], s[3]);

    // out[b, c, q] — consecutive tid -> consecutive q -> coalesced
    out[(b * NCH + c) * PPI + q] = res;
}

extern "C" void kernel_launch(void* const* d_in, const int* in_sizes, int n_in,
                              void* d_out, int out_size, void* d_ws, size_t ws_size,
                              hipStream_t stream) {
    const float* x    = (const float*)d_in[0];
    const float* lut0 = (const float*)d_in[1];
    const float* lut1 = (const float*)d_in[2];
    const float* lut2 = (const float*)d_in[3];
    const int*   idx0 = (const int*)d_in[4];
    const int*   idx1 = (const int*)d_in[5];
    const int*   idx2 = (const int*)d_in[6];
    float* out = (float*)d_out;

    dim3 grid(NPATCH / THREADS, NCH);   // 98 x 64
    dim3 block(THREADS);
    dwn_conv_lut_kernel<<<grid, block, 0, stream>>>(x, lut0, lut1, lut2,
                                                    idx0, idx1, idx2, out);
}

// Round 3
// 34.064 us; speedup vs baseline: 1.1490x; 1.0009x over previous
//
#include <hip/hip_runtime.h>
#include <math.h>

#define KK 5
#define WPOUT 28
#define PPI 784          // patches per image (28*28)
#define NCH 64
#define NPATCH 25088     // 32*784
#define THREADS 256

typedef float f32x32 __attribute__((ext_vector_type(32)));
typedef float f32x16 __attribute__((ext_vector_type(16)));

// Evaluate one 4-input LUT node.
// lutrow (LDS, 16 floats, block-uniform address): [0..7] = sigmoid(lut[2k]),
// [8..15] = sigmoid(lut[2k+1]) - sigmoid(lut[2k]).
// s0 = most significant address bit (contracted last), s3 least significant.
__device__ __forceinline__ float node_eval(const float* lutrow,
                                            float s0, float s1, float s2, float s3) {
    float v[8];
#pragma unroll
    for (int k = 0; k < 8; ++k) v[k] = fmaf(s3, lutrow[k + 8], lutrow[k]);
    float w[4];
#pragma unroll
    for (int k = 0; k < 4; ++k) w[k] = fmaf(s2, v[2 * k + 1] - v[2 * k], v[2 * k]);
    float u0 = fmaf(s1, w[1] - w[0], w[0]);
    float u1 = fmaf(s1, w[3] - w[2], w[2]);
    return fmaf(s0, u1 - u0, u0);
}

__global__ __launch_bounds__(THREADS, 4)
void dwn_conv_lut_kernel(const float* __restrict__ x,     // [32,1,32,32]
                         const float* __restrict__ lut0,  // [64,16,16]
                         const float* __restrict__ lut1,  // [64,4,16]
                         const float* __restrict__ lut2,  // [64,1,16]
                         const int*   __restrict__ idx0,  // [64,16,4]
                         const int*   __restrict__ idx1,  // [64,4,4]
                         const int*   __restrict__ idx2,  // [64,1,4]
                         float*       __restrict__ out)   // [32,64,28,28]
{
    __shared__ float l0[16][16];           // per node: e[8], d[8]
    __shared__ float l1[4][16];
    __shared__ float l2[16];

    const int tid = threadIdx.x;
    const int c   = blockIdx.y;

    // ---- stage sigmoided LUTs in (even, diff) layout: 168 pairs, one per thread ----
    if (tid < 168) {
        const float* src;
        float* dst;
        int k;
        if (tid < 128) {                     // lut0: 16 nodes * 8 pairs
            int node = tid >> 3; k = tid & 7;
            src = lut0 + (c * 16 + node) * 16;
            dst = &l0[node][0];
        } else if (tid < 160) {              // lut1: 4 nodes * 8 pairs
            int t = tid - 128;
            int node = t >> 3; k = t & 7;
            src = lut1 + (c * 4 + node) * 16;
            dst = &l1[node][0];
        } else {                             // lut2: 1 node * 8 pairs
            int t = tid - 160; k = t & 7;
            src = lut2 + c * 16;
            dst = l2;
        }
        float a = src[2 * k], b = src[2 * k + 1];
        float ea = 1.0f / (1.0f + __expf(-a));
        float eb = 1.0f / (1.0f + __expf(-b));
        dst[k]     = ea;
        dst[k + 8] = eb - ea;
    }

    // ---- load my 5x5 patch into a register-resident vector (movrel-gatherable) ----
    const int p = blockIdx.x * THREADS + tid;      // 98*256 == 25088, no tail
    const int b = p / PPI;
    const int q = p - b * PPI;
    const int i = q / WPOUT;
    const int j = q - i * WPOUT;
    const float* xb = x + b * 1024 + i * 32 + j;

    f32x32 pv;
#pragma unroll
    for (int di = 0; di < KK; ++di) {
#pragma unroll
        for (int dj = 0; dj < KK; ++dj) {
            pv[di * 5 + dj] = xb[di * 32 + dj];   // constant insert index
        }
    }

    __syncthreads();   // l0/l1/l2 ready

    // ---- layer 0: 16 nodes; gathers are uniform-index movrel reads from pv ----
    const int* id0 = idx0 + c * 64;   // block-uniform -> scalar loads
    f32x16 h0;
#pragma unroll
    for (int m = 0; m < 16; ++m) {
        const int i0 = __builtin_amdgcn_readfirstlane(id0[m * 4 + 0]);
        const int i1 = __builtin_amdgcn_readfirstlane(id0[m * 4 + 1]);
        const int i2 = __builtin_amdgcn_readfirstlane(id0[m * 4 + 2]);
        const int i3 = __builtin_amdgcn_readfirstlane(id0[m * 4 + 3]);
        h0[m] = node_eval(&l0[m][0], pv[i0], pv[i1], pv[i2], pv[i3]);
    }

    // ---- layer 1: 4 nodes; uniform-index movrel reads from h0 ----
    const int* id1 = idx1 + c * 16;
    float h1[4];
#pragma unroll
    for (int m = 0; m < 4; ++m) {
        const int i0 = __builtin_amdgcn_readfirstlane(id1[m * 4 + 0]);
        const int i1 = __builtin_amdgcn_readfirstlane(id1[m * 4 + 1]);
        const int i2 = __builtin_amdgcn_readfirstlane(id1[m * 4 + 2]);
        const int i3 = __builtin_amdgcn_readfirstlane(id1[m * 4 + 3]);
        h0[m] = h0[m]; // no-op to keep unroll clean
        h1[m] = node_eval(&l1[m][0], h0[i0], h0[i1], h0[i2], h0[i3]);
    }

    // ---- layer 2: 1 node; 4-way uniform select from h1 ----
    const int* id2 = idx2 + c * 4;
    float s[4];
#pragma unroll
    for (int jj = 0; jj < 4; ++jj) {
        const int ii = __builtin_amdgcn_readfirstlane(id2[jj]);
        s[jj] = (ii == 0) ? h1[0] : (ii == 1) ? h1[1] : (ii == 2) ? h1[2] : h1[3];
    }
    const float res = node_eval(l2, s[0], s[1], s[2], s[3]);

    // out[b, c, q] — consecutive tid -> consecutive q -> coalesced
    out[(b * NCH + c) * PPI + q] = res;
}

extern "C" void kernel_launch(void* const* d_in, const int* in_sizes, int n_in,
                              void* d_out, int out_size, void* d_ws, size_t ws_size,
                              hipStream_t stream) {
    const float* x    = (const float*)d_in[0];
    const float* lut0 = (const float*)d_in[1];
    const float* lut1 = (const float*)d_in[2];
    const float* lut2 = (const float*)d_in[3];
    const int*   idx0 = (const int*)d_in[4];
    const int*   idx1 = (const int*)d_in[5];
    const int*   idx2 = (const int*)d_in[6];
    float* out = (float*)d_out;

    dim3 grid(NPATCH / THREADS, NCH);   // 98 x 64
    dim3 block(THREADS);
    dwn_conv_lut_kernel<<<grid, block, 0, stream>>>(x, lut0, lut1, lut2,
                                                    idx0, idx1, idx2, out);
}